// Round 2
// baseline (694.390 us; speedup 1.0000x reference)
//
#include <hip/hip_runtime.h>

// out[n,o] = -sum_i |x[n,i]*mbin[i] - w[i,o]|, *mbout[o], LayerNorm over o.
// N=4096 tokens, Cin=Cout=512. VALU-bound (no fp32 MFMA; op isn't a MAC).
// R1: split-K x2 (16 waves/CU) + double-buffered LDS (1 barrier/tile, loads
// in flight under compute) to close the 38% VALU idle seen in R0.

constexpr int BM = 64, BN = 64, BK = 32;

// MODE 0: plain store, z=0 -> dst0, z=1 -> dst1.  MODE 1: atomicAdd into dst0.
template<int MODE>
__global__ __launch_bounds__(256, 4)
void adder_partial(const float* __restrict__ x, const float* __restrict__ w,
                   const float* __restrict__ mbin,
                   float* __restrict__ dst0, float* __restrict__ dst1,
                   int N, int Cin, int Cout) {
  __shared__ float xs[2][BK][BM + 1];   // transposed x tile: xs[buf][k][m]
  __shared__ float wsh[2][BK][BN];

  const int tid = threadIdx.x;
  const int tx = tid & 15;
  const int ty = tid >> 4;
  const int bm = blockIdx.x * BM;
  const int bn = blockIdx.y * BN;
  const int kh = Cin >> 1;              // 256 per split
  const int kbase = blockIdx.z * kh;
  const int NT = kh / BK;               // 8 tiles

  float acc[4][4];
  #pragma unroll
  for (int a = 0; a < 4; ++a)
    #pragma unroll
    for (int b = 0; b < 4; ++b) acc[a][b] = 0.f;

  float4 px[2], pw[2];                  // prefetch registers (x*mbin, w)

  auto LOADR = [&](int k0) {
    #pragma unroll
    for (int it = 0; it < 2; ++it) {
      const int f = tid + it * 256;
      const int xrow = f >> 3, xcol = (f & 7) << 2;
      const float4 xv = *reinterpret_cast<const float4*>(&x[(size_t)(bm + xrow) * Cin + k0 + xcol]);
      const float4 bv = *reinterpret_cast<const float4*>(&mbin[k0 + xcol]);
      px[it] = make_float4(xv.x * bv.x, xv.y * bv.y, xv.z * bv.z, xv.w * bv.w);
      const int wrow = f >> 4, wcol = (f & 15) << 2;
      pw[it] = *reinterpret_cast<const float4*>(&w[(size_t)(k0 + wrow) * Cout + bn + wcol]);
    }
  };
  auto STORES = [&](int buf) {
    #pragma unroll
    for (int it = 0; it < 2; ++it) {
      const int f = tid + it * 256;
      const int xrow = f >> 3, xcol = (f & 7) << 2;
      xs[buf][xcol + 0][xrow] = px[it].x;
      xs[buf][xcol + 1][xrow] = px[it].y;
      xs[buf][xcol + 2][xrow] = px[it].z;
      xs[buf][xcol + 3][xrow] = px[it].w;
      const int wrow = f >> 4, wcol = (f & 15) << 2;
      *reinterpret_cast<float4*>(&wsh[buf][wrow][wcol]) = pw[it];
    }
  };

  LOADR(kbase);
  STORES(0);
  int cur = 0;
  for (int t = 0; t < NT; ++t) {
    if (t + 1 < NT) LOADR(kbase + (t + 1) * BK);   // in flight during compute
    __syncthreads();                               // buf[cur] ready
    #pragma unroll
    for (int kk = 0; kk < BK; ++kk) {
      float xr[4];
      #pragma unroll
      for (int a = 0; a < 4; ++a) xr[a] = xs[cur][kk][ty * 4 + a];  // broadcast
      const float4 wv = *reinterpret_cast<const float4*>(&wsh[cur][kk][tx * 4]);
      #pragma unroll
      for (int a = 0; a < 4; ++a) {
        acc[a][0] += fabsf(xr[a] - wv.x);   // v_sub + v_add |mod|
        acc[a][1] += fabsf(xr[a] - wv.y);
        acc[a][2] += fabsf(xr[a] - wv.z);
        acc[a][3] += fabsf(xr[a] - wv.w);
      }
    }
    if (t + 1 < NT) STORES(cur ^ 1);   // buf[cur^1] last read at t-1, pre-barrier: safe
    cur ^= 1;
  }

  #pragma unroll
  for (int a = 0; a < 4; ++a) {
    const size_t off = (size_t)(bm + ty * 4 + a) * Cout + bn + tx * 4;
    if (MODE == 0) {
      float* dst = blockIdx.z ? dst1 : dst0;
      float4 o = {acc[a][0], acc[a][1], acc[a][2], acc[a][3]};
      *reinterpret_cast<float4*>(&dst[off]) = o;
    } else {
      atomicAdd(&dst0[off + 0], acc[a][0]);
      atomicAdd(&dst0[off + 1], acc[a][1]);
      atomicAdd(&dst0[off + 2], acc[a][2]);
      atomicAdd(&dst0[off + 3], acc[a][3]);
    }
  }
}

// out holds partial0 (or full sum). TWO: add partial1 from p1. Then
// v = -(sum)*mbout, LayerNorm over C=512, write out. One wave per row.
template<bool TWO>
__global__ __launch_bounds__(256)
void ln_fuse(const float* __restrict__ p1, const float* __restrict__ mbout,
             const float* __restrict__ gamma, const float* __restrict__ beta,
             float* __restrict__ out, int N, int C) {
  const int wave = threadIdx.x >> 6;
  const int lane = threadIdx.x & 63;
  const int row = blockIdx.x * 4 + wave;
  if (row >= N) return;
  float* p = out + (size_t)row * C;

  float v[8];
  {
    const float4 a = *reinterpret_cast<const float4*>(&p[lane * 8]);
    const float4 b = *reinterpret_cast<const float4*>(&p[lane * 8 + 4]);
    v[0] = a.x; v[1] = a.y; v[2] = a.z; v[3] = a.w;
    v[4] = b.x; v[5] = b.y; v[6] = b.z; v[7] = b.w;
    if (TWO) {
      const float* q = p1 + (size_t)row * C;
      const float4 c = *reinterpret_cast<const float4*>(&q[lane * 8]);
      const float4 d = *reinterpret_cast<const float4*>(&q[lane * 8 + 4]);
      v[0] += c.x; v[1] += c.y; v[2] += c.z; v[3] += c.w;
      v[4] += d.x; v[5] += d.y; v[6] += d.z; v[7] += d.w;
    }
    const float4 m0 = *reinterpret_cast<const float4*>(&mbout[lane * 8]);
    const float4 m1 = *reinterpret_cast<const float4*>(&mbout[lane * 8 + 4]);
    const float mm[8] = {m0.x, m0.y, m0.z, m0.w, m1.x, m1.y, m1.z, m1.w};
    #pragma unroll
    for (int i = 0; i < 8; ++i) v[i] = -v[i] * mm[i];
  }

  float s = 0.f;
  #pragma unroll
  for (int i = 0; i < 8; ++i) s += v[i];
  #pragma unroll
  for (int off = 32; off > 0; off >>= 1) s += __shfl_xor(s, off, 64);
  const float mean = s * (1.0f / 512.0f);

  float d2 = 0.f;
  #pragma unroll
  for (int i = 0; i < 8; ++i) {
    const float d = v[i] - mean;
    d2 += d * d;
  }
  #pragma unroll
  for (int off = 32; off > 0; off >>= 1) d2 += __shfl_xor(d2, off, 64);
  const float rstd = rsqrtf(d2 * (1.0f / 512.0f) + 1e-5f);

  const float4 g0 = *reinterpret_cast<const float4*>(&gamma[lane * 8]);
  const float4 g1 = *reinterpret_cast<const float4*>(&gamma[lane * 8 + 4]);
  const float4 b0 = *reinterpret_cast<const float4*>(&beta[lane * 8]);
  const float4 b1 = *reinterpret_cast<const float4*>(&beta[lane * 8 + 4]);
  const float gg[8] = {g0.x, g0.y, g0.z, g0.w, g1.x, g1.y, g1.z, g1.w};
  const float bb[8] = {b0.x, b0.y, b0.z, b0.w, b1.x, b1.y, b1.z, b1.w};

  float4 o0, o1;
  o0.x = (v[0] - mean) * rstd * gg[0] + bb[0];
  o0.y = (v[1] - mean) * rstd * gg[1] + bb[1];
  o0.z = (v[2] - mean) * rstd * gg[2] + bb[2];
  o0.w = (v[3] - mean) * rstd * gg[3] + bb[3];
  o1.x = (v[4] - mean) * rstd * gg[4] + bb[4];
  o1.y = (v[5] - mean) * rstd * gg[5] + bb[5];
  o1.z = (v[6] - mean) * rstd * gg[6] + bb[6];
  o1.w = (v[7] - mean) * rstd * gg[7] + bb[7];
  *reinterpret_cast<float4*>(&p[lane * 8]) = o0;
  *reinterpret_cast<float4*>(&p[lane * 8 + 4]) = o1;
}

extern "C" void kernel_launch(void* const* d_in, const int* in_sizes, int n_in,
                              void* d_out, int out_size, void* d_ws, size_t ws_size,
                              hipStream_t stream) {
  const float* x     = (const float*)d_in[0];
  const float* w     = (const float*)d_in[1];
  const float* mbin  = (const float*)d_in[2];
  const float* mbout = (const float*)d_in[3];
  const float* gamma = (const float*)d_in[4];
  const float* beta  = (const float*)d_in[5];
  float* out = (float*)d_out;

  const int Cin  = in_sizes[2];           // 512
  const int Cout = in_sizes[3];           // 512
  const int N    = in_sizes[0] / Cin;     // 4096 tokens

  dim3 grid(N / BM, Cout / BN, 2);        // 64 x 8 x 2 = 1024 blocks
  const size_t part_bytes = (size_t)N * Cout * sizeof(float);

  if (ws_size >= part_bytes) {
    float* wsb = (float*)d_ws;
    adder_partial<0><<<grid, 256, 0, stream>>>(x, w, mbin, out, wsb, N, Cin, Cout);
    ln_fuse<true><<<dim3(N / 4), 256, 0, stream>>>(wsb, mbout, gamma, beta, out, N, Cout);
  } else {
    hipMemsetAsync(d_out, 0, part_bytes, stream);   // memset node: capture-safe
    adder_partial<1><<<grid, 256, 0, stream>>>(x, w, mbin, out, out, N, Cin, Cout);
    ln_fuse<false><<<dim3(N / 4), 256, 0, stream>>>(nullptr, mbout, gamma, beta, out, N, Cout);
  }
}

// Round 5
// 157.381 us; speedup vs baseline: 4.4121x; 4.4121x over previous
//
#include <hip/hip_runtime.h>

// out[n,o] = -sum_i |x[n,i]*mbin[i] - w[i,o]|, *mbout[o], LayerNorm over o.
// N=4096 tokens, Cin=Cout=512. VALU-bound (no fp32 MFMA; op isn't a MAC).
// R5: NO split-K / NO d_ws (R4's graph-replay divergence traced to the
// split-K+workspace path; R1's plain two-kernel in-place pattern passed).
// Occupancy via tile shrink instead: BM=64 x BN=32 -> grid (64,16)=1024
// blocks = 4 blocks/CU = 16 waves/CU. Double-buffered LDS, one barrier/tile.
// LN block->row mapping XCD-matched to the adder's writers (both id%8).

constexpr int BM = 64, BN = 32, BK = 32;
constexpr int XPAD = 4;   // keeps xs row 16B-aligned for b128 reads

__global__ __launch_bounds__(256, 2)
void adder_gemm(const float* __restrict__ x, const float* __restrict__ w,
                const float* __restrict__ mbin, const float* __restrict__ mbout,
                float* __restrict__ out, int N, int Cin, int Cout) {
  __shared__ float xs[2][BK][BM + XPAD];   // transposed x tile: xs[buf][k][m]
  __shared__ float wsh[2][BK][BN];

  const int tid = threadIdx.x;
  const int tx = tid & 15;    // 16 col-groups x 2 cols
  const int ty = tid >> 4;    // 16 row-groups x 4 rows
  const int bm = blockIdx.x * BM;
  const int bn = blockIdx.y * BN;
  const int NT = Cin / BK;    // 16 tiles

  float acc[4][2];
  #pragma unroll
  for (int a = 0; a < 4; ++a) { acc[a][0] = 0.f; acc[a][1] = 0.f; }

  float4 px[2], pw;           // prefetch registers (x*mbin, w)

  auto LOADR = [&](int k0) {
    #pragma unroll
    for (int it = 0; it < 2; ++it) {
      const int f = tid + it * 256;
      const int xrow = f >> 3, xcol = (f & 7) << 2;
      const float4 xv = *reinterpret_cast<const float4*>(&x[(size_t)(bm + xrow) * Cin + k0 + xcol]);
      const float4 bv = *reinterpret_cast<const float4*>(&mbin[k0 + xcol]);
      px[it] = make_float4(xv.x * bv.x, xv.y * bv.y, xv.z * bv.z, xv.w * bv.w);
    }
    const int wrow = tid >> 3, wcol = (tid & 7) << 2;
    pw = *reinterpret_cast<const float4*>(&w[(size_t)(k0 + wrow) * Cout + bn + wcol]);
  };
  auto STORES = [&](int buf) {
    #pragma unroll
    for (int it = 0; it < 2; ++it) {
      const int f = tid + it * 256;
      const int xrow = f >> 3, xcol = (f & 7) << 2;
      xs[buf][xcol + 0][xrow] = px[it].x;
      xs[buf][xcol + 1][xrow] = px[it].y;
      xs[buf][xcol + 2][xrow] = px[it].z;
      xs[buf][xcol + 3][xrow] = px[it].w;
    }
    const int wrow = tid >> 3, wcol = (tid & 7) << 2;
    *reinterpret_cast<float4*>(&wsh[buf][wrow][wcol]) = pw;
  };

  LOADR(0);
  STORES(0);
  int cur = 0;
  for (int t = 0; t < NT; ++t) {
    if (t + 1 < NT) LOADR((t + 1) * BK);   // loads in flight under compute
    __syncthreads();                        // buf[cur] ready for all waves
    #pragma unroll
    for (int kk = 0; kk < BK; ++kk) {
      const float4 xv4 = *reinterpret_cast<const float4*>(&xs[cur][kk][ty * 4]);  // b128 bcast
      const float2 wv  = *reinterpret_cast<const float2*>(&wsh[cur][kk][tx * 2]); // b64
      const float xr[4] = {xv4.x, xv4.y, xv4.z, xv4.w};
      #pragma unroll
      for (int a = 0; a < 4; ++a) {
        acc[a][0] += fabsf(xr[a] - wv.x);   // v_sub + v_add with |.| modifier
        acc[a][1] += fabsf(xr[a] - wv.y);
      }
    }
    if (t + 1 < NT) STORES(cur ^ 1);   // buf[cur^1] last read before this tile's barrier
    cur ^= 1;
  }

  // epilogue: out = -acc * mbout (pre-LN value; LN normalizes in place)
  const float2 mb = *reinterpret_cast<const float2*>(&mbout[bn + tx * 2]);
  #pragma unroll
  for (int a = 0; a < 4; ++a) {
    float2 o;
    o.x = -acc[a][0] * mb.x;
    o.y = -acc[a][1] * mb.y;
    *reinterpret_cast<float2*>(&out[(size_t)(bm + ty * 4 + a) * Cout + bn + tx * 2]) = o;
  }
}

// In-place LayerNorm over C=512. One wave per row, 4 rows/block, grid N/4.
// Row assignment XCD-matched to the adder's writers: rows of adder-block bx
// were all written on XCD bx%8 (gridDim.x=64 is a multiple of 8), so pick
// rows with bx%8 == our block id%8 -> dirty lines are in OUR XCD's L2.
__global__ __launch_bounds__(256)
void ln_rows(float* __restrict__ out, const float* __restrict__ gamma,
             const float* __restrict__ beta, int N, int C) {
  const int b = blockIdx.x;
  const int xcd = b & 7;
  const int idx = b >> 3;          // 0..127 within this XCD's share
  const int bx  = xcd + 8 * (idx >> 4);   // adder row-block, bx%8 == xcd
  const int j   = idx & 15;               // which 4-row chunk of bx
  const int row0 = bx * 64 + j * 4;

  const int wave = threadIdx.x >> 6;
  const int lane = threadIdx.x & 63;
  const int row = row0 + wave;
  if (row >= N) return;
  float* p = out + (size_t)row * C;

  float v[8];
  {
    const float4 a = *reinterpret_cast<const float4*>(&p[lane * 8]);
    const float4 bq = *reinterpret_cast<const float4*>(&p[lane * 8 + 4]);
    v[0] = a.x; v[1] = a.y; v[2] = a.z; v[3] = a.w;
    v[4] = bq.x; v[5] = bq.y; v[6] = bq.z; v[7] = bq.w;
  }

  float s = 0.f;
  #pragma unroll
  for (int i = 0; i < 8; ++i) s += v[i];
  #pragma unroll
  for (int off = 32; off > 0; off >>= 1) s += __shfl_xor(s, off, 64);
  const float mean = s * (1.0f / 512.0f);

  float d2 = 0.f;
  #pragma unroll
  for (int i = 0; i < 8; ++i) {
    const float d = v[i] - mean;
    d2 += d * d;
  }
  #pragma unroll
  for (int off = 32; off > 0; off >>= 1) d2 += __shfl_xor(d2, off, 64);
  const float rstd = rsqrtf(d2 * (1.0f / 512.0f) + 1e-5f);

  const float4 g0 = *reinterpret_cast<const float4*>(&gamma[lane * 8]);
  const float4 g1 = *reinterpret_cast<const float4*>(&gamma[lane * 8 + 4]);
  const float4 b0 = *reinterpret_cast<const float4*>(&beta[lane * 8]);
  const float4 b1 = *reinterpret_cast<const float4*>(&beta[lane * 8 + 4]);
  const float gg[8] = {g0.x, g0.y, g0.z, g0.w, g1.x, g1.y, g1.z, g1.w};
  const float bb[8] = {b0.x, b0.y, b0.z, b0.w, b1.x, b1.y, b1.z, b1.w};

  float4 o0, o1;
  o0.x = (v[0] - mean) * rstd * gg[0] + bb[0];
  o0.y = (v[1] - mean) * rstd * gg[1] + bb[1];
  o0.z = (v[2] - mean) * rstd * gg[2] + bb[2];
  o0.w = (v[3] - mean) * rstd * gg[3] + bb[3];
  o1.x = (v[4] - mean) * rstd * gg[4] + bb[4];
  o1.y = (v[5] - mean) * rstd * gg[5] + bb[5];
  o1.z = (v[6] - mean) * rstd * gg[6] + bb[6];
  o1.w = (v[7] - mean) * rstd * gg[7] + bb[7];
  *reinterpret_cast<float4*>(&p[lane * 8]) = o0;
  *reinterpret_cast<float4*>(&p[lane * 8 + 4]) = o1;
}

extern "C" void kernel_launch(void* const* d_in, const int* in_sizes, int n_in,
                              void* d_out, int out_size, void* d_ws, size_t ws_size,
                              hipStream_t stream) {
  const float* x     = (const float*)d_in[0];
  const float* w     = (const float*)d_in[1];
  const float* mbin  = (const float*)d_in[2];
  const float* mbout = (const float*)d_in[3];
  const float* gamma = (const float*)d_in[4];
  const float* beta  = (const float*)d_in[5];
  float* out = (float*)d_out;

  const int Cin  = in_sizes[2];           // 512
  const int Cout = in_sizes[3];           // 512
  const int N    = in_sizes[0] / Cin;     // 4096 tokens

  dim3 grid(N / BM, Cout / BN);           // 64 x 16 = 1024 blocks = 4/CU
  adder_gemm<<<grid, 256, 0, stream>>>(x, w, mbin, mbout, out, N, Cin, Cout);
  ln_rows<<<dim3(N / 4), 256, 0, stream>>>(out, gamma, beta, N, Cout);
}